// Round 4
// baseline (2312.516 us; speedup 1.0000x reference)
//
#include <hip/hip_runtime.h>
#include <hip/hip_bf16.h>
#include <math.h>

// Problem constants (match reference)
constexpr int Bc = 2, Kc = 384, Nc = 4096, Dc = 1024;
constexpr int Hc = 150, Lc = 12, DDc = 20, NBc = 10;
constexpr int Mrows = Bc * Kc; // 768

__device__ __forceinline__ float sigmoidf_(float x) { return 1.0f / (1.0f + expf(-x)); }

// ---------------------------------------------------------------------------
// dist table: dtab[n][h] = sum_k dist_emb[n][k]*Wd[k][h] + bd[h]   (10x150)
// ---------------------------------------------------------------------------
__global__ __launch_bounds__(256) void dtab_k(const float* __restrict__ de,
                                              const float* __restrict__ Wd,
                                              const float* __restrict__ bd,
                                              float* __restrict__ dtab) {
    int idx = blockIdx.x * 256 + threadIdx.x;
    if (idx >= NBc * Hc) return;
    int n = idx / Hc, h = idx - n * Hc;
    float s = bd[h];
#pragma unroll
    for (int k = 0; k < DDc; ++k) s = fmaf(de[n * DDc + k], Wd[k * Hc + h], s);
    dtab[n * Hc + h] = s;
}

// ---------------------------------------------------------------------------
// Generic f32 GEMM: C = act(A[M,Kd] @ W[Kd,N] (+bias))
// ACT: 0 = none(+bias if given), 1 = tanh (no bias), 2 = gate:
//      g = sigmoid(acc + bias[col]); C = g*E1 + (1-g)*E2
// M multiple of 64, Kd multiple of 16. N guarded.
// ---------------------------------------------------------------------------
template <int ACT>
__global__ __launch_bounds__(256) void gemm_k(const float* __restrict__ A,
                                              const float* __restrict__ W,
                                              const float* __restrict__ bias,
                                              float* __restrict__ C,
                                              int M, int N, int Kd,
                                              const float* __restrict__ E1,
                                              const float* __restrict__ E2) {
    __shared__ float As[16][65];
    __shared__ float Ws[16][64];
    const int tid = threadIdx.x;
    const int tx = tid & 15, ty = tid >> 4;
    const int row0 = blockIdx.y * 64;
    const int col0 = blockIdx.x * 64;
    float acc[4][4] = {};
    for (int k0 = 0; k0 < Kd; k0 += 16) {
#pragma unroll
        for (int p = 0; p < 4; ++p) {
            int m = p * 16 + (tid >> 4);
            int kk = tid & 15;
            As[kk][m] = A[(size_t)(row0 + m) * Kd + k0 + kk];
        }
#pragma unroll
        for (int p = 0; p < 4; ++p) {
            int kk = p * 4 + (tid >> 6);
            int n = tid & 63;
            int col = col0 + n;
            Ws[kk][n] = (col < N) ? W[(size_t)(k0 + kk) * N + col] : 0.0f;
        }
        __syncthreads();
#pragma unroll
        for (int kk = 0; kk < 16; ++kk) {
            float a[4], bb[4];
#pragma unroll
            for (int i = 0; i < 4; ++i) a[i] = As[kk][ty * 4 + i];
#pragma unroll
            for (int j = 0; j < 4; ++j) bb[j] = Ws[kk][tx * 4 + j];
#pragma unroll
            for (int i = 0; i < 4; ++i)
#pragma unroll
                for (int j = 0; j < 4; ++j) acc[i][j] = fmaf(a[i], bb[j], acc[i][j]);
        }
        __syncthreads();
    }
#pragma unroll
    for (int i = 0; i < 4; ++i) {
        int row = row0 + ty * 4 + i;
#pragma unroll
        for (int j = 0; j < 4; ++j) {
            int col = col0 + tx * 4 + j;
            if (col >= N) continue;
            float v = acc[i][j];
            if (ACT == 0) {
                if (bias) v += bias[col];
            } else if (ACT == 1) {
                v = tanhf(v);
            } else if (ACT == 2) {
                float g = sigmoidf_(v + bias[col]);
                size_t ix = (size_t)row * N + col;
                v = g * E1[ix] + (1.0f - g) * E2[ix];
            }
            C[(size_t)row * N + col] = v;
        }
    }
}

// ---------------------------------------------------------------------------
// Batched P@U GEMM (per batch b): C[b] = (TRANS ? P[b]^T : P[b]) @ U[b], row-scaled
// P: [K,K], U: [K,D], C: [K,D], rs: [K] (1/(sum+eps))
// ---------------------------------------------------------------------------
template <bool TRANS>
__global__ __launch_bounds__(256) void gemm_pu(const float* __restrict__ Pall,
                                               const float* __restrict__ Uall,
                                               const float* __restrict__ rsall,
                                               float* __restrict__ Call) {
    const int b = blockIdx.z;
    const float* P = Pall + (size_t)b * Kc * Kc;
    const float* U = Uall + (size_t)b * Kc * Dc;
    const float* rs = rsall + (size_t)b * Kc;
    float* C = Call + (size_t)b * Kc * Dc;

    __shared__ float As[16][65];
    __shared__ float Ws[16][64];
    const int tid = threadIdx.x;
    const int tx = tid & 15, ty = tid >> 4;
    const int row0 = blockIdx.y * 64;
    const int col0 = blockIdx.x * 64;
    float acc[4][4] = {};
    for (int k0 = 0; k0 < Kc; k0 += 16) {
        if (TRANS) {
#pragma unroll
            for (int p = 0; p < 4; ++p) {
                int kk = p * 4 + (tid >> 6);
                int m = tid & 63;
                As[kk][m] = P[(size_t)(k0 + kk) * Kc + row0 + m];
            }
        } else {
#pragma unroll
            for (int p = 0; p < 4; ++p) {
                int m = p * 16 + (tid >> 4);
                int kk = tid & 15;
                As[kk][m] = P[(size_t)(row0 + m) * Kc + k0 + kk];
            }
        }
#pragma unroll
        for (int p = 0; p < 4; ++p) {
            int kk = p * 4 + (tid >> 6);
            int n = tid & 63;
            Ws[kk][n] = U[(size_t)(k0 + kk) * Dc + col0 + n];
        }
        __syncthreads();
#pragma unroll
        for (int kk = 0; kk < 16; ++kk) {
            float a[4], bb[4];
#pragma unroll
            for (int i = 0; i < 4; ++i) a[i] = As[kk][ty * 4 + i];
#pragma unroll
            for (int j = 0; j < 4; ++j) bb[j] = Ws[kk][tx * 4 + j];
#pragma unroll
            for (int i = 0; i < 4; ++i)
#pragma unroll
                for (int j = 0; j < 4; ++j) acc[i][j] = fmaf(a[i], bb[j], acc[i][j]);
        }
        __syncthreads();
    }
#pragma unroll
    for (int i = 0; i < 4; ++i) {
        int row = row0 + ty * 4 + i;
        float s = rs[row];
#pragma unroll
        for (int j = 0; j < 4; ++j) {
            int col = col0 + tx * 4 + j;
            C[(size_t)row * Dc + col] = acc[i][j] * s;
        }
    }
}

// ---------------------------------------------------------------------------
// Scorer: scores[b,i,j,:] (+)= relu(l[b,i,:] + r[b,j,:] + dtab[bucket(b,i,j),:]) @ Wo + bo
// grid: (K/16, K/16, B), 256 threads, thread = one (i,j) pair.
// ---------------------------------------------------------------------------
template <bool ADD>
__global__ __launch_bounds__(256) void scorer_k(const float* __restrict__ Lm,
                                                const float* __restrict__ Rm,
                                                const float* __restrict__ dtab,
                                                const int* __restrict__ sb,
                                                const int* __restrict__ se,
                                                const float* __restrict__ Wo,
                                                const float* __restrict__ bo,
                                                float* __restrict__ scores) {
    const int b = blockIdx.z;
    const int i0 = blockIdx.y * 16;
    const int j0 = blockIdx.x * 16;
    __shared__ float Ll[16 * 151];
    __shared__ float Rl[16 * 151];
    __shared__ float Dl[NBc * 151];
    __shared__ float Wol[Hc * Lc];
    __shared__ float bol[Lc];
    const int tid = threadIdx.x;
    for (int idx = tid; idx < 16 * Hc; idx += 256) {
        int r = idx / Hc, c = idx - r * Hc;
        Ll[r * 151 + c] = Lm[(size_t)(b * Kc + i0 + r) * Hc + c];
        Rl[r * 151 + c] = Rm[(size_t)(b * Kc + j0 + r) * Hc + c];
    }
    for (int idx = tid; idx < NBc * Hc; idx += 256) {
        int r = idx / Hc, c = idx - r * Hc;
        Dl[r * 151 + c] = dtab[r * Hc + c];
    }
    for (int idx = tid; idx < Hc * Lc; idx += 256) Wol[idx] = Wo[idx];
    if (tid < Lc) bol[tid] = bo[tid];
    __syncthreads();

    const int ty = tid >> 4, tx = tid & 15;
    const int i = i0 + ty, j = j0 + tx;
    int d = sb[b * Kc + j] - se[b * Kc + i];
    int da = d < 0 ? -d : d;
    int bucket = (da <= 4) ? da : min(31 - __clz(da) + 3, NBc - 1);
    const float* lp = &Ll[ty * 151];
    const float* rp = &Rl[tx * 151];
    const float* dp = &Dl[bucket * 151];
    float acc[Lc] = {};
    for (int h = 0; h < Hc; ++h) {
        float v = lp[h] + rp[h] + dp[h];
        v = fmaxf(v, 0.0f);
#pragma unroll
        for (int l = 0; l < Lc; ++l) acc[l] = fmaf(v, Wol[h * Lc + l], acc[l]);
    }
    size_t base = (((size_t)(b * Kc + i)) * Kc + j) * Lc;
#pragma unroll
    for (int l = 0; l < Lc; ++l) {
        float v = acc[l] + bol[l];
        if (ADD) v += scores[base + l];
        scores[base + l] = v;
    }
}

// ---------------------------------------------------------------------------
// probs[b,i,j] = sigmoid(max_l scores[b,i,j,l]) * mask[b,i,j]
// ---------------------------------------------------------------------------
__global__ __launch_bounds__(256) void probs_k(const float* __restrict__ scores,
                                               const float* __restrict__ mask,
                                               float* __restrict__ probs) {
    int idx = blockIdx.x * 256 + threadIdx.x;
    if (idx >= Bc * Kc * Kc) return;
    const float* s = scores + (size_t)idx * Lc;
    float m = s[0];
#pragma unroll
    for (int l = 1; l < Lc; ++l) m = fmaxf(m, s[l]);
    probs[idx] = sigmoidf_(m) * mask[idx];
}

// rowsum: s1inv[b*K+i] = 1/(sum_j probs[b,i,j] + 1e-7); one wave per row
__global__ __launch_bounds__(256) void rowsum_k(const float* __restrict__ probs,
                                                float* __restrict__ s1inv) {
    int row = (blockIdx.x * 256 + threadIdx.x) >> 6;
    int lane = threadIdx.x & 63;
    if (row >= Mrows) return;
    const float* p = probs + (size_t)row * Kc;
    float s = 0.0f;
    for (int j = lane; j < Kc; j += 64) s += p[j];
#pragma unroll
    for (int off = 32; off > 0; off >>= 1) s += __shfl_down(s, off);
    if (lane == 0) s1inv[row] = 1.0f / (s + 1e-7f);
}

// colsum: s2inv[b*K+j] = 1/(sum_i probs[b,i,j] + 1e-7)
__global__ __launch_bounds__(256) void colsum_k(const float* __restrict__ probs,
                                                float* __restrict__ s2inv) {
    int idx = blockIdx.x * 256 + threadIdx.x;
    if (idx >= Mrows) return;
    int b = idx / Kc, j = idx - b * Kc;
    const float* p = probs + (size_t)b * Kc * Kc + j;
    float s = 0.0f;
    for (int i = 0; i < Kc; ++i) s += p[(size_t)i * Kc];
    s2inv[idx] = 1.0f / (s + 1e-7f);
}

// cc[row] = [U[row] | c1[row] | c2[row]]
__global__ __launch_bounds__(256) void concat3_k(const float* __restrict__ U,
                                                 const float* __restrict__ c1,
                                                 const float* __restrict__ c2,
                                                 float* __restrict__ cc) {
    int row = blockIdx.x;
    size_t ub = (size_t)row * Dc, cb = (size_t)row * (3 * Dc);
    for (int c = threadIdx.x; c < Dc; c += 256) {
        cc[cb + c] = U[ub + c];
        cc[cb + Dc + c] = c1[ub + c];
        cc[cb + 2 * Dc + c] = c2[ub + c];
    }
}

__global__ __launch_bounds__(256) void concat2_k(const float* __restrict__ U,
                                                 const float* __restrict__ ct,
                                                 float* __restrict__ cg) {
    int row = blockIdx.x;
    size_t ub = (size_t)row * Dc, cb = (size_t)row * (2 * Dc);
    for (int c = threadIdx.x; c < Dc; c += 256) {
        cg[cb + c] = U[ub + c];
        cg[cb + Dc + c] = ct[ub + c];
    }
}

__global__ __launch_bounds__(256) void copy4_k(const float4* __restrict__ s,
                                               float4* __restrict__ d, int n4) {
    int i = blockIdx.x * 256 + threadIdx.x;
    if (i < n4) d[i] = s[i];
}

// scatter: numpy sequential-set semantics (sorted indices, last occurrence wins;
// invalid last occurrence writes original value => no-op)
__global__ __launch_bounds__(256) void scatter_k(const float* __restrict__ Uf,
                                                 const int* __restrict__ pidx,
                                                 const int* __restrict__ slen,
                                                 float* __restrict__ out_all) {
    int bk = blockIdx.x;
    int b = bk / Kc, k = bk - b * Kc;
    if (k >= slen[b]) return;
    int idx = pidx[bk];
    if (k + 1 < Kc && pidx[bk + 1] == idx) return; // not last occurrence in (sorted) run
    const float4* s = (const float4*)(Uf + (size_t)bk * Dc);
    float4* d = (float4*)(out_all + ((size_t)b * Nc + idx) * Dc);
    for (int c = threadIdx.x; c < Dc / 4; c += 256) d[c] = s[c];
}

// ---------------------------------------------------------------------------
extern "C" void kernel_launch(void* const* d_in, const int* in_sizes, int n_in,
                              void* d_out, int out_size, void* d_ws, size_t ws_size,
                              hipStream_t stream) {
    const float* span_vecs = (const float*)d_in[0];
    const float* all_span_vecs = (const float*)d_in[1];
    const int* span_begin = (const int*)d_in[2];
    const int* span_end = (const int*)d_in[3];
    const float* square_mask = (const float*)d_in[4];
    const int* prune_indices = (const int*)d_in[5];
    const int* span_lengths = (const int*)d_in[6];
    // d_in[7] sequence_lengths unused
    const float* Wl = (const float*)d_in[8];
    const float* bl = (const float*)d_in[9];
    const float* Wr = (const float*)d_in[10];
    const float* br = (const float*)d_in[11];
    const float* dist_emb = (const float*)d_in[12];
    const float* Wd = (const float*)d_in[13];
    const float* bd = (const float*)d_in[14];
    const float* Wo = (const float*)d_in[15];
    const float* bo = (const float*)d_in[16];
    const float* Wff1 = (const float*)d_in[17];
    const float* Wff2 = (const float*)d_in[18];
    const float* Wg = (const float*)d_in[19];
    const float* bg = (const float*)d_in[20];

    float* out_all = (float*)d_out;                    // B*N*D   = 8,388,608 floats
    float* out_u = out_all + (size_t)Bc * Nc * Dc;     // B*K*D   =   786,432
    float* out_sc = out_u + (size_t)Mrows * Dc;        // B*K*K*L = 3,538,944

    // All scratch lives inside the out_all region (needed only at the end).
    // Total: 7,606,336 floats <= 8,388,608. Zero d_ws dependence.
    float* w = out_all;
    float* LM = w;                       // 768*150
    float* RM = LM + Mrows * Hc;         // 768*150
    float* DT = RM + Mrows * Hc;         // 1500 (pad 1600)
    float* PR = DT + 1600;               // 2*384*384
    float* S1 = PR + Bc * Kc * Kc;       // 768
    float* S2 = S1 + Mrows;              // 768
    float* C1 = S2 + Mrows;              // 768*1024
    float* C2 = C1 + (size_t)Mrows * Dc; // 768*1024
    float* CC = C2 + (size_t)Mrows * Dc; // 768*3072 (reused as 768*2048)
    float* T1 = CC + (size_t)Mrows * 3 * Dc; // 768*1024
    float* CT = T1 + (size_t)Mrows * Dc;     // 768*1024
    float* UA = CT + (size_t)Mrows * Dc;     // 768*1024
    float* UB = UA + (size_t)Mrows * Dc;     // 768*1024

    dim3 blk(256);
    dim3 g_lr(3, Mrows / 64);      // N=150 -> 3 col tiles
    dim3 g_d(Dc / 64, Mrows / 64); // N=1024
    dim3 g_pu(Dc / 64, Kc / 64, Bc);
    dim3 g_sc(Kc / 16, Kc / 16, Bc);

    // dist table
    dtab_k<<<(NBc * Hc + 255) / 256, blk, 0, stream>>>(dist_emb, Wd, bd, DT);

    // initial scorer
    gemm_k<0><<<g_lr, blk, 0, stream>>>(span_vecs, Wl, bl, LM, Mrows, Hc, Dc, nullptr, nullptr);
    gemm_k<0><<<g_lr, blk, 0, stream>>>(span_vecs, Wr, br, RM, Mrows, Hc, Dc, nullptr, nullptr);
    scorer_k<false><<<g_sc, blk, 0, stream>>>(LM, RM, DT, span_begin, span_end, Wo, bo, out_sc);

    const float* Ucur = span_vecs;
    float* bufs[2] = {UA, UB};
    for (int it = 0; it < 2; ++it) {
        float* Unext = bufs[it];
        probs_k<<<(Bc * Kc * Kc + 255) / 256, blk, 0, stream>>>(out_sc, square_mask, PR);
        rowsum_k<<<Mrows / 4, blk, 0, stream>>>(PR, S1);
        colsum_k<<<(Mrows + 255) / 256, blk, 0, stream>>>(PR, S2);
        gemm_pu<false><<<g_pu, blk, 0, stream>>>(PR, Ucur, S1, C1);
        gemm_pu<true><<<g_pu, blk, 0, stream>>>(PR, Ucur, S2, C2);
        concat3_k<<<Mrows, blk, 0, stream>>>(Ucur, C1, C2, CC);
        gemm_k<1><<<g_d, blk, 0, stream>>>(CC, Wff1, nullptr, T1, Mrows, Dc, 3 * Dc, nullptr, nullptr);
        gemm_k<0><<<g_d, blk, 0, stream>>>(T1, Wff2, nullptr, CT, Mrows, Dc, Dc, nullptr, nullptr);
        concat2_k<<<Mrows, blk, 0, stream>>>(Ucur, CT, CC);
        gemm_k<2><<<g_d, blk, 0, stream>>>(CC, Wg, bg, Unext, Mrows, Dc, 2 * Dc, Ucur, CT);
        gemm_k<0><<<g_lr, blk, 0, stream>>>(Unext, Wl, bl, LM, Mrows, Hc, Dc, nullptr, nullptr);
        gemm_k<0><<<g_lr, blk, 0, stream>>>(Unext, Wr, br, RM, Mrows, Hc, Dc, nullptr, nullptr);
        scorer_k<true><<<g_sc, blk, 0, stream>>>(LM, RM, DT, span_begin, span_end, Wo, bo, out_sc);
        Ucur = Unext;
    }

    // outputs — ORDER MATTERS: save u first (scratch lives in out_all region),
    // then overwrite out_all with all_span_vecs, then scatter from the saved copy.
    copy4_k<<<((Mrows * Dc / 4) + 255) / 256, blk, 0, stream>>>(
        (const float4*)Ucur, (float4*)out_u, Mrows * Dc / 4);
    copy4_k<<<((Bc * Nc * Dc / 4) + 255) / 256, blk, 0, stream>>>(
        (const float4*)all_span_vecs, (float4*)out_all, Bc * Nc * Dc / 4);
    scatter_k<<<Mrows, blk, 0, stream>>>(out_u, prune_indices, span_lengths, out_all);
}

// Round 5
// 1038.780 us; speedup vs baseline: 2.2262x; 2.2262x over previous
//
#include <hip/hip_runtime.h>
#include <hip/hip_bf16.h>
#include <math.h>

// Problem constants (match reference)
constexpr int Bc = 2, Kc = 384, Nc = 4096, Dc = 1024;
constexpr int Hc = 150, Lc = 12, DDc = 20, NBc = 10;
constexpr int Mrows = Bc * Kc; // 768

__device__ __forceinline__ float sigmoidf_(float x) { return 1.0f / (1.0f + expf(-x)); }

// ---------------------------------------------------------------------------
// dist table: dtab[n][h] = sum_k dist_emb[n][k]*Wd[k][h] + bd[h]   (10x150)
// ---------------------------------------------------------------------------
__global__ __launch_bounds__(256) void dtab_k(const float* __restrict__ de,
                                              const float* __restrict__ Wd,
                                              const float* __restrict__ bd,
                                              float* __restrict__ dtab) {
    int idx = blockIdx.x * 256 + threadIdx.x;
    if (idx >= NBc * Hc) return;
    int n = idx / Hc, h = idx - n * Hc;
    float s = bd[h];
#pragma unroll
    for (int k = 0; k < DDc; ++k) s = fmaf(de[n * DDc + k], Wd[k * Hc + h], s);
    dtab[n * Hc + h] = s;
}

// ---------------------------------------------------------------------------
// Split-K partial GEMM: Cpart[s][row][col] = sum_{k in chunk s} A[row,k]*W[k,col]
// Tile 64 rows x 32 cols, 256 threads (4x2 per thread), grid (N/32, M/64, S).
// M multiple of 64, chunk multiple of 16, N guarded.
// ---------------------------------------------------------------------------
__global__ __launch_bounds__(256) void gemm_sk(const float* __restrict__ A,
                                               const float* __restrict__ W,
                                               float* __restrict__ Cpart,
                                               int M, int N, int Kd, int chunk) {
    __shared__ float As[16][65];
    __shared__ float Ws[16][32];
    const int tid = threadIdx.x;
    const int tx = tid & 15, ty = tid >> 4;
    const int row0 = blockIdx.y * 64;
    const int col0 = blockIdx.x * 32;
    const int s = blockIdx.z;
    const int kbeg = s * chunk;
    const int kend = min(kbeg + chunk, Kd);
    float acc[4][2] = {};
    for (int k0 = kbeg; k0 < kend; k0 += 16) {
#pragma unroll
        for (int p = 0; p < 4; ++p) {
            int m = p * 16 + (tid >> 4);
            int kk = tid & 15;
            As[kk][m] = A[(size_t)(row0 + m) * Kd + k0 + kk];
        }
#pragma unroll
        for (int p = 0; p < 2; ++p) {
            int kk = p * 8 + (tid >> 5);
            int n = tid & 31;
            int col = col0 + n;
            Ws[kk][n] = (col < N) ? W[(size_t)(k0 + kk) * N + col] : 0.0f;
        }
        __syncthreads();
#pragma unroll
        for (int kk = 0; kk < 16; ++kk) {
            float a[4], bb[2];
#pragma unroll
            for (int i = 0; i < 4; ++i) a[i] = As[kk][ty * 4 + i];
#pragma unroll
            for (int j = 0; j < 2; ++j) bb[j] = Ws[kk][tx * 2 + j];
#pragma unroll
            for (int i = 0; i < 4; ++i)
#pragma unroll
                for (int j = 0; j < 2; ++j) acc[i][j] = fmaf(a[i], bb[j], acc[i][j]);
        }
        __syncthreads();
    }
    size_t base = (size_t)s * M * N;
#pragma unroll
    for (int i = 0; i < 4; ++i) {
        int row = row0 + ty * 4 + i;
#pragma unroll
        for (int j = 0; j < 2; ++j) {
            int col = col0 + tx * 2 + j;
            if (col < N) Cpart[base + (size_t)row * N + col] = acc[i][j];
        }
    }
}

// ---------------------------------------------------------------------------
// Split-K batched P@U partial GEMM: grid (Dc/32, Kc/64, Bc*S), z = b*S + s
// Cpart[s][b][row][col] = sum_{k in chunk} (TRANS ? P[b][k][row] : P[b][row][k]) * U[b][k][col]
// ---------------------------------------------------------------------------
template <bool TRANS>
__global__ __launch_bounds__(256) void gemm_pu_sk(const float* __restrict__ Pall,
                                                  const float* __restrict__ Uall,
                                                  float* __restrict__ Cpart,
                                                  int S, int chunk) {
    const int b = blockIdx.z / S;
    const int s = blockIdx.z - b * S;
    const float* P = Pall + (size_t)b * Kc * Kc;
    const float* U = Uall + (size_t)b * Kc * Dc;

    __shared__ float As[16][65];
    __shared__ float Ws[16][32];
    const int tid = threadIdx.x;
    const int tx = tid & 15, ty = tid >> 4;
    const int row0 = blockIdx.y * 64;
    const int col0 = blockIdx.x * 32;
    const int kbeg = s * chunk;
    const int kend = min(kbeg + chunk, Kc);
    float acc[4][2] = {};
    for (int k0 = kbeg; k0 < kend; k0 += 16) {
        if (TRANS) {
#pragma unroll
            for (int p = 0; p < 4; ++p) {
                int kk = p * 4 + (tid >> 6);
                int m = tid & 63;
                As[kk][m] = P[(size_t)(k0 + kk) * Kc + row0 + m];
            }
        } else {
#pragma unroll
            for (int p = 0; p < 4; ++p) {
                int m = p * 16 + (tid >> 4);
                int kk = tid & 15;
                As[kk][m] = P[(size_t)(row0 + m) * Kc + k0 + kk];
            }
        }
#pragma unroll
        for (int p = 0; p < 2; ++p) {
            int kk = p * 8 + (tid >> 5);
            int n = tid & 31;
            Ws[kk][n] = U[(size_t)(k0 + kk) * Dc + col0 + n];
        }
        __syncthreads();
#pragma unroll
        for (int kk = 0; kk < 16; ++kk) {
            float a[4], bb[2];
#pragma unroll
            for (int i = 0; i < 4; ++i) a[i] = As[kk][ty * 4 + i];
#pragma unroll
            for (int j = 0; j < 2; ++j) bb[j] = Ws[kk][tx * 2 + j];
#pragma unroll
            for (int i = 0; i < 4; ++i)
#pragma unroll
                for (int j = 0; j < 2; ++j) acc[i][j] = fmaf(a[i], bb[j], acc[i][j]);
        }
        __syncthreads();
    }
    size_t base = (size_t)s * (Bc * Kc * Dc) + (size_t)b * Kc * Dc;
#pragma unroll
    for (int i = 0; i < 4; ++i) {
        int row = row0 + ty * 4 + i;
#pragma unroll
        for (int j = 0; j < 2; ++j) {
            int col = col0 + tx * 2 + j;
            Cpart[base + (size_t)row * Dc + col] = acc[i][j];
        }
    }
}

// ---------------------------------------------------------------------------
// Epilogue: out[idx] = act(sum_s Cpart[s][idx])
// ACT 0: +bias(optional); 1: tanh; 2: gate g=sig(v+bias[col]), out=g*E1+(1-g)*E2;
// ACT 3: v * rs[idx / N]  (row-scaled, for P@U)
// ---------------------------------------------------------------------------
template <int ACT>
__global__ __launch_bounds__(256) void ep_k(const float* __restrict__ Cp,
                                            const float* __restrict__ bias,
                                            const float* __restrict__ rs,
                                            const float* __restrict__ E1,
                                            const float* __restrict__ E2,
                                            float* __restrict__ out,
                                            int total, int N, int S) {
    int idx = blockIdx.x * 256 + threadIdx.x;
    if (idx >= total) return;
    float v = 0.0f;
    for (int s = 0; s < S; ++s) v += Cp[(size_t)s * total + idx];
    if (ACT == 0) {
        if (bias) {
            int row = idx / N;
            v += bias[idx - row * N];
        }
    } else if (ACT == 1) {
        v = tanhf(v);
    } else if (ACT == 2) {
        int row = idx / N;
        float g = sigmoidf_(v + bias[idx - row * N]);
        v = g * E1[idx] + (1.0f - g) * E2[idx];
    } else if (ACT == 3) {
        v *= rs[idx / N];
    }
    out[idx] = v;
}

// ---------------------------------------------------------------------------
// Scorer: scores[b,i,j,:] (+)= relu(l[b,i,:] + r[b,j,:] + dtab[bucket(b,i,j),:]) @ Wo + bo
// grid: (K/16, K/16, B), 256 threads, thread = one (i,j) pair.
// ---------------------------------------------------------------------------
template <bool ADD>
__global__ __launch_bounds__(256) void scorer_k(const float* __restrict__ Lm,
                                                const float* __restrict__ Rm,
                                                const float* __restrict__ dtab,
                                                const int* __restrict__ sb,
                                                const int* __restrict__ se,
                                                const float* __restrict__ Wo,
                                                const float* __restrict__ bo,
                                                float* __restrict__ scores) {
    const int b = blockIdx.z;
    const int i0 = blockIdx.y * 16;
    const int j0 = blockIdx.x * 16;
    __shared__ float Ll[16 * 151];
    __shared__ float Rl[16 * 151];
    __shared__ float Dl[NBc * 151];
    __shared__ float Wol[Hc * Lc];
    __shared__ float bol[Lc];
    const int tid = threadIdx.x;
    for (int idx = tid; idx < 16 * Hc; idx += 256) {
        int r = idx / Hc, c = idx - r * Hc;
        Ll[r * 151 + c] = Lm[(size_t)(b * Kc + i0 + r) * Hc + c];
        Rl[r * 151 + c] = Rm[(size_t)(b * Kc + j0 + r) * Hc + c];
    }
    for (int idx = tid; idx < NBc * Hc; idx += 256) {
        int r = idx / Hc, c = idx - r * Hc;
        Dl[r * 151 + c] = dtab[r * Hc + c];
    }
    for (int idx = tid; idx < Hc * Lc; idx += 256) Wol[idx] = Wo[idx];
    if (tid < Lc) bol[tid] = bo[tid];
    __syncthreads();

    const int ty = tid >> 4, tx = tid & 15;
    const int i = i0 + ty, j = j0 + tx;
    int d = sb[b * Kc + j] - se[b * Kc + i];
    int da = d < 0 ? -d : d;
    int bucket = (da <= 4) ? da : min(31 - __clz(da) + 3, NBc - 1);
    const float* lp = &Ll[ty * 151];
    const float* rp = &Rl[tx * 151];
    const float* dp = &Dl[bucket * 151];
    float acc[Lc] = {};
    for (int h = 0; h < Hc; ++h) {
        float v = lp[h] + rp[h] + dp[h];
        v = fmaxf(v, 0.0f);
#pragma unroll
        for (int l = 0; l < Lc; ++l) acc[l] = fmaf(v, Wol[h * Lc + l], acc[l]);
    }
    size_t base = (((size_t)(b * Kc + i)) * Kc + j) * Lc;
#pragma unroll
    for (int l = 0; l < Lc; ++l) {
        float v = acc[l] + bol[l];
        if (ADD) v += scores[base + l];
        scores[base + l] = v;
    }
}

// ---------------------------------------------------------------------------
// probs[b,i,j] = sigmoid(max_l scores[b,i,j,l]) * mask[b,i,j]
// ---------------------------------------------------------------------------
__global__ __launch_bounds__(256) void probs_k(const float* __restrict__ scores,
                                               const float* __restrict__ mask,
                                               float* __restrict__ probs) {
    int idx = blockIdx.x * 256 + threadIdx.x;
    if (idx >= Bc * Kc * Kc) return;
    const float* s = scores + (size_t)idx * Lc;
    float m = s[0];
#pragma unroll
    for (int l = 1; l < Lc; ++l) m = fmaxf(m, s[l]);
    probs[idx] = sigmoidf_(m) * mask[idx];
}

// rowsum: s1inv[b*K+i] = 1/(sum_j probs[b,i,j] + 1e-7); one wave per row
__global__ __launch_bounds__(256) void rowsum_k(const float* __restrict__ probs,
                                                float* __restrict__ s1inv) {
    int row = (blockIdx.x * 256 + threadIdx.x) >> 6;
    int lane = threadIdx.x & 63;
    if (row >= Mrows) return;
    const float* p = probs + (size_t)row * Kc;
    float s = 0.0f;
    for (int j = lane; j < Kc; j += 64) s += p[j];
#pragma unroll
    for (int off = 32; off > 0; off >>= 1) s += __shfl_down(s, off);
    if (lane == 0) s1inv[row] = 1.0f / (s + 1e-7f);
}

// colsum: s2inv[b*K+j] = 1/(sum_i probs[b,i,j] + 1e-7)
__global__ __launch_bounds__(256) void colsum_k(const float* __restrict__ probs,
                                                float* __restrict__ s2inv) {
    int idx = blockIdx.x * 256 + threadIdx.x;
    if (idx >= Mrows) return;
    int b = idx / Kc, j = idx - b * Kc;
    const float* p = probs + (size_t)b * Kc * Kc + j;
    float s = 0.0f;
    for (int i = 0; i < Kc; ++i) s += p[(size_t)i * Kc];
    s2inv[idx] = 1.0f / (s + 1e-7f);
}

// cc[row] = [U[row] | c1[row] | c2[row]]
__global__ __launch_bounds__(256) void concat3_k(const float* __restrict__ U,
                                                 const float* __restrict__ c1,
                                                 const float* __restrict__ c2,
                                                 float* __restrict__ cc) {
    int row = blockIdx.x;
    size_t ub = (size_t)row * Dc, cb = (size_t)row * (3 * Dc);
    for (int c = threadIdx.x; c < Dc; c += 256) {
        cc[cb + c] = U[ub + c];
        cc[cb + Dc + c] = c1[ub + c];
        cc[cb + 2 * Dc + c] = c2[ub + c];
    }
}

__global__ __launch_bounds__(256) void concat2_k(const float* __restrict__ U,
                                                 const float* __restrict__ ct,
                                                 float* __restrict__ cg) {
    int row = blockIdx.x;
    size_t ub = (size_t)row * Dc, cb = (size_t)row * (2 * Dc);
    for (int c = threadIdx.x; c < Dc; c += 256) {
        cg[cb + c] = U[ub + c];
        cg[cb + Dc + c] = ct[ub + c];
    }
}

__global__ __launch_bounds__(256) void copy4_k(const float4* __restrict__ s,
                                               float4* __restrict__ d, int n4) {
    int i = blockIdx.x * 256 + threadIdx.x;
    if (i < n4) d[i] = s[i];
}

// scatter: numpy sequential-set semantics (sorted indices, last occurrence wins;
// invalid last occurrence writes original value => no-op)
__global__ __launch_bounds__(256) void scatter_k(const float* __restrict__ Uf,
                                                 const int* __restrict__ pidx,
                                                 const int* __restrict__ slen,
                                                 float* __restrict__ out_all) {
    int bk = blockIdx.x;
    int b = bk / Kc, k = bk - b * Kc;
    if (k >= slen[b]) return;
    int idx = pidx[bk];
    if (k + 1 < Kc && pidx[bk + 1] == idx) return; // not last occurrence in (sorted) run
    const float4* s = (const float4*)(Uf + (size_t)bk * Dc);
    float4* d = (float4*)(out_all + ((size_t)b * Nc + idx) * Dc);
    for (int c = threadIdx.x; c < Dc / 4; c += 256) d[c] = s[c];
}

// ---------------------------------------------------------------------------
extern "C" void kernel_launch(void* const* d_in, const int* in_sizes, int n_in,
                              void* d_out, int out_size, void* d_ws, size_t ws_size,
                              hipStream_t stream) {
    const float* span_vecs = (const float*)d_in[0];
    const float* all_span_vecs = (const float*)d_in[1];
    const int* span_begin = (const int*)d_in[2];
    const int* span_end = (const int*)d_in[3];
    const float* square_mask = (const float*)d_in[4];
    const int* prune_indices = (const int*)d_in[5];
    const int* span_lengths = (const int*)d_in[6];
    // d_in[7] sequence_lengths unused
    const float* Wl = (const float*)d_in[8];
    const float* bl = (const float*)d_in[9];
    const float* Wr = (const float*)d_in[10];
    const float* br = (const float*)d_in[11];
    const float* dist_emb = (const float*)d_in[12];
    const float* Wd = (const float*)d_in[13];
    const float* bd = (const float*)d_in[14];
    const float* Wo = (const float*)d_in[15];
    const float* bo = (const float*)d_in[16];
    const float* Wff1 = (const float*)d_in[17];
    const float* Wff2 = (const float*)d_in[18];
    const float* Wg = (const float*)d_in[19];
    const float* bg = (const float*)d_in[20];

    float* out_all = (float*)d_out;                    // B*N*D   = 8,388,608 floats
    float* out_u = out_all + (size_t)Bc * Nc * Dc;     // B*K*D   =   786,432
    float* out_sc = out_u + (size_t)Mrows * Dc;        // B*K*K*L = 3,538,944

    // All scratch lives inside the out_all region (needed only at the end).
    // Total: 7,606,336 floats <= 8,388,608. Zero d_ws dependence.
    float* w = out_all;
    float* LM = w;                       // 768*150
    float* RM = LM + Mrows * Hc;         // 768*150
    float* DT = RM + Mrows * Hc;         // 1500 (pad 1600)
    float* PR = DT + 1600;               // 2*384*384
    float* S1 = PR + Bc * Kc * Kc;       // 768
    float* S2 = S1 + Mrows;              // 768
    float* C1 = S2 + Mrows;              // 768*1024
    float* C2 = C1 + (size_t)Mrows * Dc; // 768*1024
    float* CC = C2 + (size_t)Mrows * Dc; // 768*3072 (reused as 768*2048)
    float* T1 = CC + (size_t)Mrows * 3 * Dc; // 768*1024
    float* CT = T1 + (size_t)Mrows * Dc;     // 768*1024
    float* UA = CT + (size_t)Mrows * Dc;     // 768*1024
    float* UB = UA + (size_t)Mrows * Dc;     // 768*1024

    // Split-K partial buffers (aliased onto dead regions — liveness audited):
    // CpF = [C1,C2] (1,572,864 floats): C1/C2 dead whenever FF/l-r GEMMs run.
    // CpPU = CC (2,359,296 floats): CC dead while P@U GEMMs run (pre-concat).
    float* CpF = C1;
    float* CpPU = CC;

    const int MN_D = Mrows * Dc;   // 786,432
    const int MN_H = Mrows * Hc;   // 115,200

    dim3 blk(256);
    dim3 g_ff(Dc / 32, Mrows / 64, 2);   // S=2 -> 768 blocks
    dim3 g_lr(5, Mrows / 64, 8);         // N=150 -> 5 col tiles, S=8 -> 480 blocks
    dim3 g_pu(Dc / 32, Kc / 64, Bc * 2); // S=2 -> 768 blocks
    dim3 g_sc(Kc / 16, Kc / 16, Bc);

    // dist table
    dtab_k<<<(NBc * Hc + 255) / 256, blk, 0, stream>>>(dist_emb, Wd, bd, DT);

    // initial scorer projections (split-K + bias epilogue)
    gemm_sk<<<g_lr, blk, 0, stream>>>(span_vecs, Wl, CpF, Mrows, Hc, Dc, 128);
    ep_k<0><<<(MN_H + 255) / 256, blk, 0, stream>>>(CpF, bl, nullptr, nullptr, nullptr, LM, MN_H, Hc, 8);
    gemm_sk<<<g_lr, blk, 0, stream>>>(span_vecs, Wr, CpF, Mrows, Hc, Dc, 128);
    ep_k<0><<<(MN_H + 255) / 256, blk, 0, stream>>>(CpF, br, nullptr, nullptr, nullptr, RM, MN_H, Hc, 8);
    scorer_k<false><<<g_sc, blk, 0, stream>>>(LM, RM, DT, span_begin, span_end, Wo, bo, out_sc);

    const float* Ucur = span_vecs;
    float* bufs[2] = {UA, UB};
    for (int it = 0; it < 2; ++it) {
        float* Unext = bufs[it];
        probs_k<<<(Bc * Kc * Kc + 255) / 256, blk, 0, stream>>>(out_sc, square_mask, PR);
        rowsum_k<<<Mrows / 4, blk, 0, stream>>>(PR, S1);
        colsum_k<<<(Mrows + 255) / 256, blk, 0, stream>>>(PR, S2);
        // ctxt1 = P@U row-scaled; ctxt2 = P^T@U col-sum-scaled (partials in CC region)
        gemm_pu_sk<false><<<g_pu, blk, 0, stream>>>(PR, Ucur, CpPU, 2, 192);
        ep_k<3><<<(MN_D + 255) / 256, blk, 0, stream>>>(CpPU, nullptr, S1, nullptr, nullptr, C1, MN_D, Dc, 2);
        gemm_pu_sk<true><<<g_pu, blk, 0, stream>>>(PR, Ucur, CpPU, 2, 192);
        ep_k<3><<<(MN_D + 255) / 256, blk, 0, stream>>>(CpPU, nullptr, S2, nullptr, nullptr, C2, MN_D, Dc, 2);
        concat3_k<<<Mrows, blk, 0, stream>>>(Ucur, C1, C2, CC);
        // FF: T1 = tanh(CC @ Wff1); CT = T1 @ Wff2   (partials in C1/C2 region)
        gemm_sk<<<g_ff, blk, 0, stream>>>(CC, Wff1, CpF, Mrows, Dc, 3 * Dc, 1536);
        ep_k<1><<<(MN_D + 255) / 256, blk, 0, stream>>>(CpF, nullptr, nullptr, nullptr, nullptr, T1, MN_D, Dc, 2);
        gemm_sk<<<g_ff, blk, 0, stream>>>(T1, Wff2, CpF, Mrows, Dc, Dc, 512);
        ep_k<0><<<(MN_D + 255) / 256, blk, 0, stream>>>(CpF, nullptr, nullptr, nullptr, nullptr, CT, MN_D, Dc, 2);
        concat2_k<<<Mrows, blk, 0, stream>>>(Ucur, CT, CC);
        // gate: g = sigmoid([U|CT]@Wg + bg); Unext = g*U + (1-g)*CT
        gemm_sk<<<g_ff, blk, 0, stream>>>(CC, Wg, CpF, Mrows, Dc, 2 * Dc, 1024);
        ep_k<2><<<(MN_D + 255) / 256, blk, 0, stream>>>(CpF, bg, nullptr, Ucur, CT, Unext, MN_D, Dc, 2);
        // next scorer projections
        gemm_sk<<<g_lr, blk, 0, stream>>>(Unext, Wl, CpF, Mrows, Hc, Dc, 128);
        ep_k<0><<<(MN_H + 255) / 256, blk, 0, stream>>>(CpF, bl, nullptr, nullptr, nullptr, LM, MN_H, Hc, 8);
        gemm_sk<<<g_lr, blk, 0, stream>>>(Unext, Wr, CpF, Mrows, Hc, Dc, 128);
        ep_k<0><<<(MN_H + 255) / 256, blk, 0, stream>>>(CpF, br, nullptr, nullptr, nullptr, RM, MN_H, Hc, 8);
        scorer_k<true><<<g_sc, blk, 0, stream>>>(LM, RM, DT, span_begin, span_end, Wo, bo, out_sc);
        Ucur = Unext;
    }

    // outputs — ORDER MATTERS: save u first (scratch lives in out_all region),
    // then overwrite out_all with all_span_vecs, then scatter from the saved copy.
    copy4_k<<<((Mrows * Dc / 4) + 255) / 256, blk, 0, stream>>>(
        (const float4*)Ucur, (float4*)out_u, Mrows * Dc / 4);
    copy4_k<<<((Bc * Nc * Dc / 4) + 255) / 256, blk, 0, stream>>>(
        (const float4*)all_span_vecs, (float4*)out_all, Bc * Nc * Dc / 4);
    scatter_k<<<Mrows, blk, 0, stream>>>(out_u, prune_indices, span_lengths, out_all);
}

// Round 6
// 854.399 us; speedup vs baseline: 2.7066x; 1.2158x over previous
//
#include <hip/hip_runtime.h>
#include <math.h>

// Problem constants (match reference)
constexpr int Bc = 2, Kc = 384, Nc = 4096, Dc = 1024;
constexpr int Hc = 150, Lc = 12, DDc = 20, NBc = 10;
constexpr int Mrows = Bc * Kc; // 768

typedef __attribute__((ext_vector_type(8))) unsigned short ushort8;
typedef __attribute__((ext_vector_type(8))) short short8;
typedef __attribute__((ext_vector_type(4))) float f32x4;

__device__ __forceinline__ float sigmoidf_(float x) { return 1.0f / (1.0f + expf(-x)); }

// f32 -> bf16 (RNE)
__device__ __forceinline__ unsigned short f2b(float f) {
    unsigned u = __float_as_uint(f);
    unsigned r = (u + 0x7fffu + ((u >> 16) & 1u)) >> 16;
    return (unsigned short)r;
}

// ---------------------------------------------------------------------------
// elementwise f32 -> bf16 convert (grid-stride)
// ---------------------------------------------------------------------------
__global__ __launch_bounds__(256) void cvt_k(const float* __restrict__ s,
                                             unsigned short* __restrict__ d, int n) {
    for (int i = blockIdx.x * 256 + threadIdx.x; i < n; i += gridDim.x * 256)
        d[i] = f2b(s[i]);
}

// ---------------------------------------------------------------------------
// dist table: dtab[n][h] = dist_emb[n] @ Wd + bd   (10x150, f32)
// ---------------------------------------------------------------------------
__global__ __launch_bounds__(256) void dtab_k(const float* __restrict__ de,
                                              const float* __restrict__ Wd,
                                              const float* __restrict__ bd,
                                              float* __restrict__ dtab) {
    int idx = blockIdx.x * 256 + threadIdx.x;
    if (idx >= NBc * Hc) return;
    int n = idx / Hc, h = idx - n * Hc;
    float s = bd[h];
#pragma unroll
    for (int k = 0; k < DDc; ++k) s = fmaf(de[n * DDc + k], Wd[k * Hc + h], s);
    dtab[n * Hc + h] = s;
}

// ---------------------------------------------------------------------------
// MFMA bf16 GEMM, 64x64 tile, 4 waves (each 32x32 = 2x2 16x16 frags), K-step 32.
// A: up to NSRC bf16 sources, each [rows][1024] when NSRC>1 (k-tile never
//    straddles the 1024 boundaries since 1024 % 32 == 0); arstride = row stride.
// W: bf16 [Kd][N] row-major (row stride N).
// EPI: 0: outf = v + bias[col]                      (f32, stride N)
//      1: outb = bf16(tanh(v))
//      2: outf = v ; outb = bf16(v)
//      3: g = sigmoid(v + bias[col]); r = g*E1 + (1-g)*E2 (E1/E2 f32 stride N);
//         outf = r ; outb = bf16(r)
//      4: outb = bf16(v * rs[row])
// blockIdx.z batching via *Batch element strides (PU uses z = batch).
// Correctness note: A-frag and B-frag use the IDENTICAL (lane,j)->k mapping,
// so any k-permutation assumption cancels in the MFMA dot product. C/D layout
// is the HW-verified row=(lane>>4)*4+reg, col=lane&15.
// ---------------------------------------------------------------------------
template <int NSRC, int EPI>
__global__ __launch_bounds__(256) void mfma_gemm(
    const unsigned short* __restrict__ a0, const unsigned short* __restrict__ a1,
    const unsigned short* __restrict__ a2, int arstride, long aBatch,
    const unsigned short* __restrict__ W, long wBatch,
    int N, int Kd,
    const float* __restrict__ bias, const float* __restrict__ rs, long rsBatch,
    const float* __restrict__ E1, const float* __restrict__ E2,
    float* __restrict__ outf, unsigned short* __restrict__ outb, long oBatch) {
    constexpr int LDA = 40; // padded stride (shorts): 80B rows -> <=2-way banks, 16B aligned
    __shared__ unsigned short Als[64 * LDA];
    __shared__ unsigned short Bls[64 * LDA];

    const int z = blockIdx.z;
    a0 += (size_t)z * aBatch;
    W += (size_t)z * wBatch;
    if (rs) rs += (size_t)z * rsBatch;
    if (outb) outb += (size_t)z * oBatch;
    if (outf) outf += (size_t)z * oBatch;

    const int tid = threadIdx.x;
    const int wave = tid >> 6, lane = tid & 63;
    const int wr = wave >> 1, wc = wave & 1;
    const int l15 = lane & 15, lg = lane >> 4;
    const int row0 = blockIdx.y * 64, col0 = blockIdx.x * 64;

    f32x4 acc[2][2] = {};

    const int arow = tid >> 2;           // 0..63
    const int akc = (tid & 3) * 8;       // 0,8,16,24
    const int bcol = tid & 63;           // 0..63
    const int bkb = (tid >> 6) * 8;      // 0,8,16,24

    for (int k0 = 0; k0 < Kd; k0 += 32) {
        // --- stage A tile [64 rows][32 k] ---
        {
            int kglob = k0 + akc;
            const unsigned short* asrc = a0;
            int kl = kglob;
            if (NSRC > 1) {
                int s = kglob >> 10;
                kl = kglob & 1023;
                asrc = (s == 0) ? a0 : ((s == 1 || NSRC == 2) ? a1 : a2);
            }
            ushort8 av = *reinterpret_cast<const ushort8*>(
                asrc + (size_t)(row0 + arow) * arstride + kl);
            *reinterpret_cast<ushort8*>(&Als[arow * LDA + akc]) = av;
        }
        // --- stage B tile transposed: Bls[col][k] ---
        {
            int col = col0 + bcol;
            ushort8 bv;
#pragma unroll
            for (int j = 0; j < 8; ++j)
                bv[j] = (col < N) ? W[(size_t)(k0 + bkb + j) * N + col] : (unsigned short)0;
            *reinterpret_cast<ushort8*>(&Bls[bcol * LDA + bkb]) = bv;
        }
        __syncthreads();
        // --- fragments + MFMA ---
        short8 af[2], bf[2];
#pragma unroll
        for (int m = 0; m < 2; ++m)
            af[m] = *reinterpret_cast<const short8*>(&Als[(wr * 32 + m * 16 + l15) * LDA + lg * 8]);
#pragma unroll
        for (int n = 0; n < 2; ++n)
            bf[n] = *reinterpret_cast<const short8*>(&Bls[(wc * 32 + n * 16 + l15) * LDA + lg * 8]);
#pragma unroll
        for (int m = 0; m < 2; ++m)
#pragma unroll
            for (int n = 0; n < 2; ++n)
                acc[m][n] = __builtin_amdgcn_mfma_f32_16x16x32_bf16(af[m], bf[n], acc[m][n], 0, 0, 0);
        __syncthreads();
    }

    // --- epilogue ---
#pragma unroll
    for (int m = 0; m < 2; ++m) {
#pragma unroll
        for (int n = 0; n < 2; ++n) {
#pragma unroll
            for (int r = 0; r < 4; ++r) {
                int row = row0 + wr * 32 + m * 16 + lg * 4 + r;
                int col = col0 + wc * 32 + n * 16 + l15;
                if (col >= N) continue;
                float v = acc[m][n][r];
                size_t ix = (size_t)row * N + col;
                if (EPI == 0) {
                    outf[ix] = v + bias[col];
                } else if (EPI == 1) {
                    outb[ix] = f2b(tanhf(v));
                } else if (EPI == 2) {
                    outf[ix] = v;
                    outb[ix] = f2b(v);
                } else if (EPI == 3) {
                    float g = sigmoidf_(v + bias[col]);
                    float rv = g * E1[ix] + (1.0f - g) * E2[ix];
                    outf[ix] = rv;
                    outb[ix] = f2b(rv);
                } else if (EPI == 4) {
                    outb[ix] = f2b(v * rs[row]);
                }
            }
        }
    }
}

// ---------------------------------------------------------------------------
// Scorer: scores[b,i,j,:] (+)= relu(l[b,i,:] + r[b,j,:] + dtab[bucket]) @ Wo + bo
// ---------------------------------------------------------------------------
template <bool ADD>
__global__ __launch_bounds__(256) void scorer_k(const float* __restrict__ Lm,
                                                const float* __restrict__ Rm,
                                                const float* __restrict__ dtab,
                                                const int* __restrict__ sb,
                                                const int* __restrict__ se,
                                                const float* __restrict__ Wo,
                                                const float* __restrict__ bo,
                                                float* __restrict__ scores) {
    const int b = blockIdx.z;
    const int i0 = blockIdx.y * 16;
    const int j0 = blockIdx.x * 16;
    __shared__ float Ll[16 * 151];
    __shared__ float Rl[16 * 151];
    __shared__ float Dl[NBc * 151];
    __shared__ float Wol[Hc * Lc];
    __shared__ float bol[Lc];
    const int tid = threadIdx.x;
    for (int idx = tid; idx < 16 * Hc; idx += 256) {
        int r = idx / Hc, c = idx - r * Hc;
        Ll[r * 151 + c] = Lm[(size_t)(b * Kc + i0 + r) * Hc + c];
        Rl[r * 151 + c] = Rm[(size_t)(b * Kc + j0 + r) * Hc + c];
    }
    for (int idx = tid; idx < NBc * Hc; idx += 256) {
        int r = idx / Hc, c = idx - r * Hc;
        Dl[r * 151 + c] = dtab[r * Hc + c];
    }
    for (int idx = tid; idx < Hc * Lc; idx += 256) Wol[idx] = Wo[idx];
    if (tid < Lc) bol[tid] = bo[tid];
    __syncthreads();

    const int ty = tid >> 4, tx = tid & 15;
    const int i = i0 + ty, j = j0 + tx;
    int d = sb[b * Kc + j] - se[b * Kc + i];
    int da = d < 0 ? -d : d;
    int bucket = (da <= 4) ? da : min(31 - __clz(da) + 3, NBc - 1);
    const float* lp = &Ll[ty * 151];
    const float* rp = &Rl[tx * 151];
    const float* dp = &Dl[bucket * 151];
    float acc[Lc] = {};
    for (int h = 0; h < Hc; ++h) {
        float v = lp[h] + rp[h] + dp[h];
        v = fmaxf(v, 0.0f);
#pragma unroll
        for (int l = 0; l < Lc; ++l) acc[l] = fmaf(v, Wol[h * Lc + l], acc[l]);
    }
    size_t base = (((size_t)(b * Kc + i)) * Kc + j) * Lc;
#pragma unroll
    for (int l = 0; l < Lc; ++l) {
        float v = acc[l] + bol[l];
        if (ADD) v += scores[base + l];
        scores[base + l] = v;
    }
}

// ---------------------------------------------------------------------------
// probs: p = sigmoid(max_l scores)*mask -> PRf (f32), PRbf (bf16), PRTbf (bf16 transposed)
// ---------------------------------------------------------------------------
__global__ __launch_bounds__(256) void probs_k(const float* __restrict__ scores,
                                               const float* __restrict__ mask,
                                               float* __restrict__ PRf,
                                               unsigned short* __restrict__ PRbf,
                                               unsigned short* __restrict__ PRTbf) {
    int idx = blockIdx.x * 256 + threadIdx.x;
    if (idx >= Bc * Kc * Kc) return;
    const float* s = scores + (size_t)idx * Lc;
    float m = s[0];
#pragma unroll
    for (int l = 1; l < Lc; ++l) m = fmaxf(m, s[l]);
    float p = sigmoidf_(m) * mask[idx];
    PRf[idx] = p;
    unsigned short pb = f2b(p);
    PRbf[idx] = pb;
    int b = idx / (Kc * Kc);
    int rem = idx - b * Kc * Kc;
    int i = rem / Kc, j = rem - i * Kc;
    PRTbf[(size_t)b * Kc * Kc + (size_t)j * Kc + i] = pb;
}

// rowsum: s1inv[row] = 1/(sum_j PRf[row][j] + 1e-7); one wave per row
__global__ __launch_bounds__(256) void rowsum_k(const float* __restrict__ probs,
                                                float* __restrict__ s1inv) {
    int row = (blockIdx.x * 256 + threadIdx.x) >> 6;
    int lane = threadIdx.x & 63;
    if (row >= Mrows) return;
    const float* p = probs + (size_t)row * Kc;
    float s = 0.0f;
    for (int j = lane; j < Kc; j += 64) s += p[j];
#pragma unroll
    for (int off = 32; off > 0; off >>= 1) s += __shfl_down(s, off);
    if (lane == 0) s1inv[row] = 1.0f / (s + 1e-7f);
}

// colsum: s2inv[b*K+j] = 1/(sum_i PRf[b][i][j] + 1e-7)
__global__ __launch_bounds__(256) void colsum_k(const float* __restrict__ probs,
                                                float* __restrict__ s2inv) {
    int idx = blockIdx.x * 256 + threadIdx.x;
    if (idx >= Mrows) return;
    int b = idx / Kc, j = idx - b * Kc;
    const float* p = probs + (size_t)b * Kc * Kc + j;
    float s = 0.0f;
    for (int i = 0; i < Kc; ++i) s += p[(size_t)i * Kc];
    s2inv[idx] = 1.0f / (s + 1e-7f);
}

__global__ __launch_bounds__(256) void copy4_k(const float4* __restrict__ s,
                                               float4* __restrict__ d, int n4) {
    int i = blockIdx.x * 256 + threadIdx.x;
    if (i < n4) d[i] = s[i];
}

// scatter: numpy sequential-set semantics (sorted indices, last occurrence wins;
// invalid last occurrence writes original value => no-op)
__global__ __launch_bounds__(256) void scatter_k(const float* __restrict__ Uf,
                                                 const int* __restrict__ pidx,
                                                 const int* __restrict__ slen,
                                                 float* __restrict__ out_all) {
    int bk = blockIdx.x;
    int b = bk / Kc, k = bk - b * Kc;
    if (k >= slen[b]) return;
    int idx = pidx[bk];
    if (k + 1 < Kc && pidx[bk + 1] == idx) return;
    const float4* s = (const float4*)(Uf + (size_t)bk * Dc);
    float4* d = (float4*)(out_all + ((size_t)b * Nc + idx) * Dc);
    for (int c = threadIdx.x; c < Dc / 4; c += 256) d[c] = s[c];
}

// ---------------------------------------------------------------------------
extern "C" void kernel_launch(void* const* d_in, const int* in_sizes, int n_in,
                              void* d_out, int out_size, void* d_ws, size_t ws_size,
                              hipStream_t stream) {
    const float* span_vecs = (const float*)d_in[0];
    const float* all_span_vecs = (const float*)d_in[1];
    const int* span_begin = (const int*)d_in[2];
    const int* span_end = (const int*)d_in[3];
    const float* square_mask = (const float*)d_in[4];
    const int* prune_indices = (const int*)d_in[5];
    const int* span_lengths = (const int*)d_in[6];
    const float* Wl = (const float*)d_in[8];
    const float* bl = (const float*)d_in[9];
    const float* Wr = (const float*)d_in[10];
    const float* br = (const float*)d_in[11];
    const float* dist_emb = (const float*)d_in[12];
    const float* Wd = (const float*)d_in[13];
    const float* bd = (const float*)d_in[14];
    const float* Wo = (const float*)d_in[15];
    const float* bo = (const float*)d_in[16];
    const float* Wff1 = (const float*)d_in[17];
    const float* Wff2 = (const float*)d_in[18];
    const float* Wg = (const float*)d_in[19];
    const float* bg = (const float*)d_in[20];

    float* out_all = (float*)d_out;                    // B*N*D   = 8,388,608 floats
    float* out_u = out_all + (size_t)Bc * Nc * Dc;     // B*K*D   =   786,432
    float* out_sc = out_u + (size_t)Mrows * Dc;        // B*K*K*L = 3,538,944

    // Scratch inside out_all (dead until final copy). Offsets in float-slots,
    // all multiples of 64 (16B-aligned). Total 7,661,632 <= 8,388,608.
    float* w = out_all;
    float* DT = w;                          // 1,600
    float* PRf = w + 1600;                  // 294,912
    float* S1 = w + 296512;                 // 768
    float* S2 = w + 297280;                 // 768
    float* CT = w + 298048;                 // 786,432
    float* UA = w + 1084480;                // 786,432
    float* LM = w + 1870912;                // 115,200
    float* RM = w + 1986112;                // 115,200
    unsigned short* UbfA = (unsigned short*)(w + 2101312);   // 786,432 bf16
    unsigned short* UbfB = (unsigned short*)(w + 2494528);   // 786,432 bf16
    unsigned short* C1bf = (unsigned short*)(w + 2887744);   // 786,432 bf16 (aliased as CTbf)
    unsigned short* C2bf = (unsigned short*)(w + 3280960);   // 786,432 bf16
    unsigned short* T1bf = (unsigned short*)(w + 3674176);   // 786,432 bf16
    unsigned short* PRbf = (unsigned short*)(w + 4067392);   // 294,912 bf16
    unsigned short* PRTbf = (unsigned short*)(w + 4214848);  // 294,912 bf16
    unsigned short* Wff1b = (unsigned short*)(w + 4362304);  // 3,145,728 bf16
    unsigned short* Wff2b = (unsigned short*)(w + 5935168);  // 1,048,576 bf16
    unsigned short* Wgb = (unsigned short*)(w + 6459456);    // 2,097,152 bf16
    unsigned short* Wlb = (unsigned short*)(w + 7508032);    // 153,600 bf16
    unsigned short* Wrb = (unsigned short*)(w + 7584832);    // 153,600 bf16
    unsigned short* CTbf = C1bf; // alias: C1 dead once FF1 done; CTbf written by FF2

    // UB aliased onto out_u: final u lands in place, no copy needed.
    float* UB = out_u;

    dim3 blk(256);
    dim3 g_sc(Kc / 16, Kc / 16, Bc);
    dim3 g_d(16, 12, 1);   // N=1024, M=768
    dim3 g_lr(3, 12, 1);   // N=150 (guarded)
    dim3 g_pu(16, 6, 2);   // N=1024, M=384 per batch, z=batch

    // weight / input bf16 conversion
    cvt_k<<<2048, blk, 0, stream>>>(span_vecs, UbfA, Mrows * Dc);
    cvt_k<<<2048, blk, 0, stream>>>(Wl, Wlb, Dc * Hc);
    cvt_k<<<2048, blk, 0, stream>>>(Wr, Wrb, Dc * Hc);
    cvt_k<<<2048, blk, 0, stream>>>(Wff1, Wff1b, 3 * Dc * Dc);
    cvt_k<<<2048, blk, 0, stream>>>(Wff2, Wff2b, Dc * Dc);
    cvt_k<<<2048, blk, 0, stream>>>(Wg, Wgb, 2 * Dc * Dc);
    dtab_k<<<(NBc * Hc + 255) / 256, blk, 0, stream>>>(dist_emb, Wd, bd, DT);

    // initial scorer projections + scorer
    mfma_gemm<1, 0><<<g_lr, blk, 0, stream>>>(UbfA, nullptr, nullptr, Dc, 0, Wlb, 0, Hc, Dc,
                                              bl, nullptr, 0, nullptr, nullptr, LM, nullptr, 0);
    mfma_gemm<1, 0><<<g_lr, blk, 0, stream>>>(UbfA, nullptr, nullptr, Dc, 0, Wrb, 0, Hc, Dc,
                                              br, nullptr, 0, nullptr, nullptr, RM, nullptr, 0);
    scorer_k<false><<<g_sc, blk, 0, stream>>>(LM, RM, DT, span_begin, span_end, Wo, bo, out_sc);

    const float* UcurF = span_vecs;
    unsigned short* Ubf = UbfA;
    float* UnextF_arr[2] = {UA, UB};
    unsigned short* UbfN_arr[2] = {UbfB, UbfA};
    for (int it = 0; it < 2; ++it) {
        float* UnextF = UnextF_arr[it];
        unsigned short* UbfN = UbfN_arr[it];
        probs_k<<<(Bc * Kc * Kc + 255) / 256, blk, 0, stream>>>(out_sc, square_mask, PRf, PRbf, PRTbf);
        rowsum_k<<<Mrows / 4, blk, 0, stream>>>(PRf, S1);
        colsum_k<<<(Mrows + 255) / 256, blk, 0, stream>>>(PRf, S2);
        // ctxt1 = rowscale(P @ U), ctxt2 = colscale(P^T @ U)  (bf16 out)
        mfma_gemm<1, 4><<<g_pu, blk, 0, stream>>>(PRbf, nullptr, nullptr, Kc, (long)Kc * Kc,
                                                  Ubf, (long)Kc * Dc, Dc, Kc,
                                                  nullptr, S1, Kc, nullptr, nullptr,
                                                  nullptr, C1bf, (long)Kc * Dc);
        mfma_gemm<1, 4><<<g_pu, blk, 0, stream>>>(PRTbf, nullptr, nullptr, Kc, (long)Kc * Kc,
                                                  Ubf, (long)Kc * Dc, Dc, Kc,
                                                  nullptr, S2, Kc, nullptr, nullptr,
                                                  nullptr, C2bf, (long)Kc * Dc);
        // T1 = tanh([U|C1|C2] @ Wff1)  (bf16)
        mfma_gemm<3, 1><<<g_d, blk, 0, stream>>>(Ubf, C1bf, C2bf, Dc, 0, Wff1b, 0, Dc, 3 * Dc,
                                                 nullptr, nullptr, 0, nullptr, nullptr,
                                                 nullptr, T1bf, 0);
        // CT = T1 @ Wff2  (f32 + bf16)
        mfma_gemm<1, 2><<<g_d, blk, 0, stream>>>(T1bf, nullptr, nullptr, Dc, 0, Wff2b, 0, Dc, Dc,
                                                 nullptr, nullptr, 0, nullptr, nullptr,
                                                 CT, CTbf, 0);
        // gate: g = sig([U|CT]@Wg + bg); Unext = g*U + (1-g)*CT  (f32 + bf16)
        mfma_gemm<2, 3><<<g_d, blk, 0, stream>>>(Ubf, CTbf, nullptr, Dc, 0, Wgb, 0, Dc, 2 * Dc,
                                                 bg, nullptr, 0, UcurF, CT,
                                                 UnextF, UbfN, 0);
        // next scorer projections + scorer (residual add)
        mfma_gemm<1, 0><<<g_lr, blk, 0, stream>>>(UbfN, nullptr, nullptr, Dc, 0, Wlb, 0, Hc, Dc,
                                                  bl, nullptr, 0, nullptr, nullptr, LM, nullptr, 0);
        mfma_gemm<1, 0><<<g_lr, blk, 0, stream>>>(UbfN, nullptr, nullptr, Dc, 0, Wrb, 0, Hc, Dc,
                                                  br, nullptr, 0, nullptr, nullptr, RM, nullptr, 0);
        scorer_k<true><<<g_sc, blk, 0, stream>>>(LM, RM, DT, span_begin, span_end, Wo, bo, out_sc);
        UcurF = UnextF;
        Ubf = UbfN;
    }

    // final u already in out_u (UB alias). Fill out_all, then scatter.
    copy4_k<<<((Bc * Nc * Dc / 4) + 255) / 256, blk, 0, stream>>>(
        (const float4*)all_span_vecs, (float4*)out_all, Bc * Nc * Dc / 4);
    scatter_k<<<Mrows, blk, 0, stream>>>(out_u, prune_indices, span_lengths, out_all);
}

// Round 8
// 609.843 us; speedup vs baseline: 3.7920x; 1.4010x over previous
//
#include <hip/hip_runtime.h>
#include <math.h>

// Problem constants (match reference)
constexpr int Bc = 2, Kc = 384, Nc = 4096, Dc = 1024;
constexpr int Hc = 150, Lc = 12, DDc = 20, NBc = 10;
constexpr int Mrows = Bc * Kc; // 768

typedef __attribute__((ext_vector_type(8))) unsigned short ushort8;
typedef __attribute__((ext_vector_type(8))) short short8;
typedef __attribute__((ext_vector_type(4))) float f32x4;

__device__ __forceinline__ float sigmoidf_(float x) { return 1.0f / (1.0f + expf(-x)); }

// f32 -> bf16 (RNE)
__device__ __forceinline__ unsigned short f2b(float f) {
    unsigned u = __float_as_uint(f);
    unsigned r = (u + 0x7fffu + ((u >> 16) & 1u)) >> 16;
    return (unsigned short)r;
}

__global__ __launch_bounds__(256) void cvt_k(const float* __restrict__ s,
                                             unsigned short* __restrict__ d, int n) {
    for (int i = blockIdx.x * 256 + threadIdx.x; i < n; i += gridDim.x * 256)
        d[i] = f2b(s[i]);
}

// pack [Wl|Wr] -> Wlrb[k][300] bf16, and blr[300] = [bl|br] f32
__global__ __launch_bounds__(256) void cvtlr_k(const float* __restrict__ Wl,
                                               const float* __restrict__ Wr,
                                               const float* __restrict__ bl,
                                               const float* __restrict__ br,
                                               unsigned short* __restrict__ Wlrb,
                                               float* __restrict__ blr) {
    int idx = blockIdx.x * 256 + threadIdx.x;
    if (idx < Hc) { blr[idx] = bl[idx]; blr[Hc + idx] = br[idx]; }
    if (idx >= Dc * Hc) return;
    int k = idx / Hc, h = idx - k * Hc;
    Wlrb[k * (2 * Hc) + h] = f2b(Wl[idx]);
    Wlrb[k * (2 * Hc) + Hc + h] = f2b(Wr[idx]);
}

// dist table: dtab[n][h] = dist_emb[n] @ Wd + bd   (10x150, f32)
__global__ __launch_bounds__(256) void dtab_k(const float* __restrict__ de,
                                              const float* __restrict__ Wd,
                                              const float* __restrict__ bd,
                                              float* __restrict__ dtab) {
    int idx = blockIdx.x * 256 + threadIdx.x;
    if (idx >= NBc * Hc) return;
    int n = idx / Hc, h = idx - n * Hc;
    float s = bd[h];
#pragma unroll
    for (int k = 0; k < DDc; ++k) s = fmaf(de[n * DDc + k], Wd[k * Hc + h], s);
    dtab[n * Hc + h] = s;
}

// ---------------------------------------------------------------------------
// MFMA bf16 GEMM, 32x32 tile, 4 waves (each one 16x16 frag), K-step 64.
// A: up to NSRC bf16 sources, each [rows][1024] when NSRC>1; arstride = row stride.
// W: bf16 [Kd][N] row-major. z-batching: a0 += z*aBatch, W += (z&wmask)*wBatch,
// rs += z*rsBatch, outb/outf += z*oBatch (element strides).
// EPI: 0 outf=v+bias[col]; 1 outb=bf16(tanh v); 2 outf=v,outb=bf16(v);
//      3 gate g=sig(v+bias), r=g*E1+(1-g)*E2, outf=r,outb=bf16(r); 4 outb=bf16(v*rs[row])
// A-frag and B-frag use the IDENTICAL (lane,j)->k mapping (k-permutation cancels).
// C/D: row=(lane>>4)*4+reg, col=lane&15 (HW-verified m89).
// ---------------------------------------------------------------------------
template <int NSRC, int EPI>
__global__ __launch_bounds__(256) void mfma_gemm(
    const unsigned short* __restrict__ a0, const unsigned short* __restrict__ a1,
    const unsigned short* __restrict__ a2, int arstride, long aBatch,
    const unsigned short* __restrict__ W, long wBatch, int wmask,
    int N, int Kd,
    const float* __restrict__ bias, const float* __restrict__ rs, long rsBatch,
    const float* __restrict__ E1, const float* __restrict__ E2,
    float* __restrict__ outf, unsigned short* __restrict__ outb, long oBatch) {
    constexpr int LDA = 72; // shorts; 144B rows: 16B-aligned, only 2-way bank alias
    __shared__ unsigned short Als[32 * LDA];
    __shared__ unsigned short Bls[32 * LDA];

    const int z = blockIdx.z;
    a0 += (size_t)z * aBatch;
    W += (size_t)(z & wmask) * wBatch;
    if (rs) rs += (size_t)z * rsBatch;
    if (outb) outb += (size_t)z * oBatch;
    if (outf) outf += (size_t)z * oBatch;

    const int tid = threadIdx.x;
    const int wave = tid >> 6, lane = tid & 63;
    const int wr = wave >> 1, wc = wave & 1;
    const int l15 = lane & 15, lg = lane >> 4;
    const int row0 = blockIdx.y * 32, col0 = blockIdx.x * 32;

    f32x4 acc = {};

    // staging roles: threads 0-127 stage A (32 rows x 64 k), 128-255 stage B
    const int ar = (tid & 127) >> 2;        // 0..31
    const int akc = (tid & 3) * 16;         // 0,16,32,48 (16 shorts per thread)
    const int bcol = (tid & 127) >> 2;      // 0..31
    const int bkb = (tid & 3) * 16;         // 0..48

    for (int k0 = 0; k0 < Kd; k0 += 64) {
        if (tid < 128) {
            int kglob = k0 + akc;
            const unsigned short* asrc = a0;
            int kl = kglob;
            if (NSRC > 1) {
                int s = kglob >> 10;
                kl = kglob & 1023;
                asrc = (s == 0) ? a0 : ((s == 1 || NSRC == 2) ? a1 : a2);
            }
            const unsigned short* p = asrc + (size_t)(row0 + ar) * arstride + kl;
            *reinterpret_cast<ushort8*>(&Als[ar * LDA + akc]) =
                *reinterpret_cast<const ushort8*>(p);
            *reinterpret_cast<ushort8*>(&Als[ar * LDA + akc + 8]) =
                *reinterpret_cast<const ushort8*>(p + 8);
        } else {
            int col = col0 + bcol;
            ushort8 bv0, bv1;
#pragma unroll
            for (int j = 0; j < 8; ++j) {
                bv0[j] = (col < N) ? W[(size_t)(k0 + bkb + j) * N + col] : (unsigned short)0;
                bv1[j] = (col < N) ? W[(size_t)(k0 + bkb + 8 + j) * N + col] : (unsigned short)0;
            }
            *reinterpret_cast<ushort8*>(&Bls[bcol * LDA + bkb]) = bv0;
            *reinterpret_cast<ushort8*>(&Bls[bcol * LDA + bkb + 8]) = bv1;
        }
        __syncthreads();
#pragma unroll
        for (int h = 0; h < 2; ++h) {
            short8 af = *reinterpret_cast<const short8*>(
                &Als[(wr * 16 + l15) * LDA + h * 32 + lg * 8]);
            short8 bf = *reinterpret_cast<const short8*>(
                &Bls[(wc * 16 + l15) * LDA + h * 32 + lg * 8]);
            acc = __builtin_amdgcn_mfma_f32_16x16x32_bf16(af, bf, acc, 0, 0, 0);
        }
        __syncthreads();
    }

#pragma unroll
    for (int r = 0; r < 4; ++r) {
        int row = row0 + wr * 16 + lg * 4 + r;
        int col = col0 + wc * 16 + l15;
        if (col >= N) continue;
        float v = acc[r];
        size_t ix = (size_t)row * N + col;
        if (EPI == 0) {
            outf[ix] = v + bias[col];
        } else if (EPI == 1) {
            outb[ix] = f2b(tanhf(v));
        } else if (EPI == 2) {
            outf[ix] = v;
            outb[ix] = f2b(v);
        } else if (EPI == 3) {
            float g = sigmoidf_(v + bias[col]);
            float rv = g * E1[ix] + (1.0f - g) * E2[ix];
            outf[ix] = rv;
            outb[ix] = f2b(rv);
        } else if (EPI == 4) {
            outb[ix] = f2b(v * rs[row]);
        }
    }
}

// ---------------------------------------------------------------------------
// Scorer: scores[b,i,j,:] (+)= relu(l[b,i,:] + r[b,j,:] + dtab[bucket]) @ Wo + bo
// Lm/Rm have row stride lst (packed [l|r] matrix).
// ---------------------------------------------------------------------------
template <bool ADD>
__global__ __launch_bounds__(256) void scorer_k(const float* __restrict__ Lm,
                                                const float* __restrict__ Rm,
                                                int lst,
                                                const float* __restrict__ dtab,
                                                const int* __restrict__ sb,
                                                const int* __restrict__ se,
                                                const float* __restrict__ Wo,
                                                const float* __restrict__ bo,
                                                float* __restrict__ scores) {
    const int b = blockIdx.z;
    const int i0 = blockIdx.y * 16;
    const int j0 = blockIdx.x * 16;
    __shared__ float Ll[16 * 151];
    __shared__ float Rl[16 * 151];
    __shared__ float Dl[NBc * 151];
    __shared__ float Wol[Hc * Lc];
    __shared__ float bol[Lc];
    const int tid = threadIdx.x;
    for (int idx = tid; idx < 16 * Hc; idx += 256) {
        int r = idx / Hc, c = idx - r * Hc;
        Ll[r * 151 + c] = Lm[(size_t)(b * Kc + i0 + r) * lst + c];
        Rl[r * 151 + c] = Rm[(size_t)(b * Kc + j0 + r) * lst + c];
    }
    for (int idx = tid; idx < NBc * Hc; idx += 256) {
        int r = idx / Hc, c = idx - r * Hc;
        Dl[r * 151 + c] = dtab[r * Hc + c];
    }
    for (int idx = tid; idx < Hc * Lc; idx += 256) Wol[idx] = Wo[idx];
    if (tid < Lc) bol[tid] = bo[tid];
    __syncthreads();

    const int ty = tid >> 4, tx = tid & 15;
    const int i = i0 + ty, j = j0 + tx;
    int d = sb[b * Kc + j] - se[b * Kc + i];
    int da = d < 0 ? -d : d;
    int bucket = (da <= 4) ? da : min(31 - __clz(da) + 3, NBc - 1);
    const float* lp = &Ll[ty * 151];
    const float* rp = &Rl[tx * 151];
    const float* dp = &Dl[bucket * 151];
    float acc[Lc] = {};
    for (int h = 0; h < Hc; ++h) {
        float v = lp[h] + rp[h] + dp[h];
        v = fmaxf(v, 0.0f);
#pragma unroll
        for (int l = 0; l < Lc; ++l) acc[l] = fmaf(v, Wol[h * Lc + l], acc[l]);
    }
    size_t base = (((size_t)(b * Kc + i)) * Kc + j) * Lc;
#pragma unroll
    for (int l = 0; l < Lc; ++l) {
        float v = acc[l] + bol[l];
        if (ADD) v += scores[base + l];
        scores[base + l] = v;
    }
}

// probs -> PRf (f32), PRbf (bf16), PRTbf (bf16 transposed)
__global__ __launch_bounds__(256) void probs_k(const float* __restrict__ scores,
                                               const float* __restrict__ mask,
                                               float* __restrict__ PRf,
                                               unsigned short* __restrict__ PRbf,
                                               unsigned short* __restrict__ PRTbf) {
    int idx = blockIdx.x * 256 + threadIdx.x;
    if (idx >= Bc * Kc * Kc) return;
    const float* s = scores + (size_t)idx * Lc;
    float m = s[0];
#pragma unroll
    for (int l = 1; l < Lc; ++l) m = fmaxf(m, s[l]);
    float p = sigmoidf_(m) * mask[idx];
    PRf[idx] = p;
    unsigned short pb = f2b(p);
    PRbf[idx] = pb;
    int b = idx / (Kc * Kc);
    int rem = idx - b * Kc * Kc;
    int i = rem / Kc, j = rem - i * Kc;
    PRTbf[(size_t)b * Kc * Kc + (size_t)j * Kc + i] = pb;
}

// rowsum: s1inv[row] = 1/(sum_j PRf[row][j] + 1e-7); one wave per row
__global__ __launch_bounds__(256) void rowsum_k(const float* __restrict__ probs,
                                                float* __restrict__ s1inv) {
    int row = (blockIdx.x * 256 + threadIdx.x) >> 6;
    int lane = threadIdx.x & 63;
    if (row >= Mrows) return;
    const float* p = probs + (size_t)row * Kc;
    float s = 0.0f;
    for (int j = lane; j < Kc; j += 64) s += p[j];
#pragma unroll
    for (int off = 32; off > 0; off >>= 1) s += __shfl_down(s, off);
    if (lane == 0) s1inv[row] = 1.0f / (s + 1e-7f);
}

// colsum: s2inv[b*K+j] = 1/(sum_i PRf[b][i][j] + 1e-7)
__global__ __launch_bounds__(256) void colsum_k(const float* __restrict__ probs,
                                                float* __restrict__ s2inv) {
    int idx = blockIdx.x * 256 + threadIdx.x;
    if (idx >= Mrows) return;
    int b = idx / Kc, j = idx - b * Kc;
    const float* p = probs + (size_t)b * Kc * Kc + j;
    float s = 0.0f;
    for (int i = 0; i < Kc; ++i) s += p[(size_t)i * Kc];
    s2inv[idx] = 1.0f / (s + 1e-7f);
}

__global__ __launch_bounds__(256) void copy4_k(const float4* __restrict__ s,
                                               float4* __restrict__ d, int n4) {
    int i = blockIdx.x * 256 + threadIdx.x;
    if (i < n4) d[i] = s[i];
}

// scatter: numpy sequential-set semantics
__global__ __launch_bounds__(256) void scatter_k(const float* __restrict__ Uf,
                                                 const int* __restrict__ pidx,
                                                 const int* __restrict__ slen,
                                                 float* __restrict__ out_all) {
    int bk = blockIdx.x;
    int b = bk / Kc, k = bk - b * Kc;
    if (k >= slen[b]) return;
    int idx = pidx[bk];
    if (k + 1 < Kc && pidx[bk + 1] == idx) return;
    const float4* s = (const float4*)(Uf + (size_t)bk * Dc);
    float4* d = (float4*)(out_all + ((size_t)b * Nc + idx) * Dc);
    for (int c = threadIdx.x; c < Dc / 4; c += 256) d[c] = s[c];
}

// ---------------------------------------------------------------------------
extern "C" void kernel_launch(void* const* d_in, const int* in_sizes, int n_in,
                              void* d_out, int out_size, void* d_ws, size_t ws_size,
                              hipStream_t stream) {
    const float* span_vecs = (const float*)d_in[0];
    const float* all_span_vecs = (const float*)d_in[1];
    const int* span_begin = (const int*)d_in[2];
    const int* span_end = (const int*)d_in[3];
    const float* square_mask = (const float*)d_in[4];
    const int* prune_indices = (const int*)d_in[5];
    const int* span_lengths = (const int*)d_in[6];
    const float* Wl = (const float*)d_in[8];
    const float* bl = (const float*)d_in[9];
    const float* Wr = (const float*)d_in[10];
    const float* br = (const float*)d_in[11];
    const float* dist_emb = (const float*)d_in[12];
    const float* Wd = (const float*)d_in[13];
    const float* bd = (const float*)d_in[14];
    const float* Wo = (const float*)d_in[15];
    const float* bo = (const float*)d_in[16];
    const float* Wff1 = (const float*)d_in[17];
    const float* Wff2 = (const float*)d_in[18];
    const float* Wg = (const float*)d_in[19];
    const float* bg = (const float*)d_in[20];

    float* out_all = (float*)d_out;                    // B*N*D   = 8,388,608 floats
    float* out_u = out_all + (size_t)Bc * Nc * Dc;     // B*K*D
    float* out_sc = out_u + (size_t)Mrows * Dc;        // B*K*K*L

    // Scratch inside out_all (dead until final copy); offsets in float slots.
    // ADJACENCY REQUIRED by fused-PU z-batching (all verified in SHORTS):
    //   PRTbf = PRbf + 294,912 sh (= +147,456 fl)   <- was the round-7 bug
    //   C2bf  = C1bf + 786,432 sh;  S2 = S1 + 768 fl
    float* w = out_all;
    float* DT = w;                                          // 1,600
    float* PRf = w + 1600;                                  // 147,456
    float* S1 = w + 149056;                                 // 768
    float* S2 = w + 149824;                                 // 768 (= S1+768)
    float* CT = w + 150592;                                 // 786,432
    float* UA = w + 937024;                                 // 786,432
    float* LRM = w + 1723456;                               // 768*300 = 230,400
    unsigned short* UbfA = (unsigned short*)(w + 1953856);  // 786,432 sh
    unsigned short* UbfB = (unsigned short*)(w + 2347072);  // 786,432 sh
    unsigned short* C1bf = (unsigned short*)(w + 2740288);  // 786,432 sh
    unsigned short* C2bf = (unsigned short*)(w + 3133504);  // 786,432 sh (= C1bf + 786,432 sh)
    unsigned short* T1bf = (unsigned short*)(w + 3526720);  // 786,432 sh
    unsigned short* PRbf = (unsigned short*)(w + 3919936);  // 294,912 sh -> ends fl 4,067,392
    unsigned short* PRTbf = (unsigned short*)(w + 4067392); // 294,912 sh (= PRbf + 294,912 sh) FIXED
    unsigned short* Wff1b = (unsigned short*)(w + 4214848); // 3,145,728 sh -> ends fl 5,787,712
    unsigned short* Wff2b = (unsigned short*)(w + 5787712); // 1,048,576 sh -> ends fl 6,312,000
    unsigned short* Wgb = (unsigned short*)(w + 6312000);   // 2,097,152 sh -> ends fl 7,360,576
    unsigned short* Wlrb = (unsigned short*)(w + 7360576);  // 307,200 sh -> ends fl 7,514,176
    float* blr = w + 7514176;                               // 320 -> ends 7,514,496 <= 8,388,608
    unsigned short* CTbf = C1bf; // alias: ctxt1-bf16 dead once FF1 consumed it
    float* UB = out_u;           // final u lands in place

    const long KK = (long)Kc * Kc;   // 147,456 (element stride per z for P)
    const long KD = (long)Kc * Dc;   // 393,216 (element stride per z for U/ctxt)

    dim3 blk(256);
    dim3 g_sc(Kc / 16, Kc / 16, Bc);
    dim3 g_d(32, 24, 1);    // 32x32 tiles: N=1024, M=768 -> 768 blocks
    dim3 g_lr(10, 24, 1);   // N=300 guarded -> 240 blocks
    dim3 g_pu(32, 12, 4);   // per-batch M=384; z = {P b0, P b1, PT b0, PT b1} -> 1536 blocks

    // conversions
    cvt_k<<<2048, blk, 0, stream>>>(span_vecs, UbfA, Mrows * Dc);
    cvt_k<<<2048, blk, 0, stream>>>(Wff1, Wff1b, 3 * Dc * Dc);
    cvt_k<<<2048, blk, 0, stream>>>(Wff2, Wff2b, Dc * Dc);
    cvt_k<<<2048, blk, 0, stream>>>(Wg, Wgb, 2 * Dc * Dc);
    cvtlr_k<<<(Dc * Hc + 255) / 256, blk, 0, stream>>>(Wl, Wr, bl, br, Wlrb, blr);
    dtab_k<<<(NBc * Hc + 255) / 256, blk, 0, stream>>>(dist_emb, Wd, bd, DT);

    // initial l|r projection + scorer
    mfma_gemm<1, 0><<<g_lr, blk, 0, stream>>>(UbfA, nullptr, nullptr, Dc, 0, Wlrb, 0, 0,
                                              2 * Hc, Dc, blr, nullptr, 0, nullptr, nullptr,
                                              LRM, nullptr, 0);
    scorer_k<false><<<g_sc, blk, 0, stream>>>(LRM, LRM + Hc, 2 * Hc, DT, span_begin, span_end,
                                              Wo, bo, out_sc);

    const float* UcurF = span_vecs;
    unsigned short* Ubf = UbfA;
    float* UnextF_arr[2] = {UA, UB};
    unsigned short* UbfN_arr[2] = {UbfB, UbfA};
    for (int it = 0; it < 2; ++it) {
        float* UnextF = UnextF_arr[it];
        unsigned short* UbfN = UbfN_arr[it];
        probs_k<<<(Bc * Kc * Kc + 255) / 256, blk, 0, stream>>>(out_sc, square_mask, PRf, PRbf, PRTbf);
        rowsum_k<<<Mrows / 4, blk, 0, stream>>>(PRf, S1);
        colsum_k<<<(Mrows + 255) / 256, blk, 0, stream>>>(PRf, S2);
        // ctxt1/ctxt2 in ONE dispatch: z -> A=PRbf+z*KK ({P b0, P b1, PT b0, PT b1}),
        // W=Ubf+(z&1)*KD, rs=S1+z*Kc ({S1 b0, S1 b1, S2 b0, S2 b1}), outb=C1bf+z*KD.
        mfma_gemm<1, 4><<<g_pu, blk, 0, stream>>>(PRbf, nullptr, nullptr, Kc, KK,
                                                  Ubf, KD, 1, Dc, Kc,
                                                  nullptr, S1, Kc, nullptr, nullptr,
                                                  nullptr, C1bf, KD);
        // T1 = tanh([U|C1|C2] @ Wff1)
        mfma_gemm<3, 1><<<g_d, blk, 0, stream>>>(Ubf, C1bf, C2bf, Dc, 0, Wff1b, 0, 0,
                                                 Dc, 3 * Dc, nullptr, nullptr, 0, nullptr, nullptr,
                                                 nullptr, T1bf, 0);
        // CT = T1 @ Wff2 (f32 + bf16)
        mfma_gemm<1, 2><<<g_d, blk, 0, stream>>>(T1bf, nullptr, nullptr, Dc, 0, Wff2b, 0, 0,
                                                 Dc, Dc, nullptr, nullptr, 0, nullptr, nullptr,
                                                 CT, CTbf, 0);
        // gate
        mfma_gemm<2, 3><<<g_d, blk, 0, stream>>>(Ubf, CTbf, nullptr, Dc, 0, Wgb, 0, 0,
                                                 Dc, 2 * Dc, bg, nullptr, 0, UcurF, CT,
                                                 UnextF, UbfN, 0);
        // next l|r + scorer (residual add)
        mfma_gemm<1, 0><<<g_lr, blk, 0, stream>>>(UbfN, nullptr, nullptr, Dc, 0, Wlrb, 0, 0,
                                                  2 * Hc, Dc, blr, nullptr, 0, nullptr, nullptr,
                                                  LRM, nullptr, 0);
        scorer_k<true><<<g_sc, blk, 0, stream>>>(LRM, LRM + Hc, 2 * Hc, DT, span_begin, span_end,
                                                 Wo, bo, out_sc);
        UcurF = UnextF;
        Ubf = UbfN;
    }

    // final u already in out_u (UB alias). Fill out_all, then scatter.
    copy4_k<<<((Bc * Nc * Dc / 4) + 255) / 256, blk, 0, stream>>>(
        (const float4*)all_span_vecs, (float4*)out_all, Bc * Nc * Dc / 4);
    scatter_k<<<Mrows, blk, 0, stream>>>(out_u, prune_indices, span_lengths, out_all);
}